// Round 1
// baseline (307.469 us; speedup 1.0000x reference)
//
#include <hip/hip_runtime.h>
#include <math.h>

// ReSkipBlockGroup router: fused rms-norm scoring + online-softmax routing
// over n=6 completed blocks, merged with a partial block.
//
// Shapes: blocks [6, B*T, 1024] fp32, partial [B*T, 1024] fp32,
// w_query/norm_weight [1024] fp32. Output: hidden [B*T,1024] ++ entropy [B*T].
//
// Strategy: one 64-lane wave per token; each lane owns 4 coalesced float4
// chunks (16 floats). Single pass over the 6 block vectors using online
// softmax (running max/lse + rescaled routed accumulator in registers).
// Memory-bound: ~269 MB total traffic -> roofline ~43 us @ 6.3 TB/s.

#define D 1024
#define NBLK 6
#define C4 4              // float4 chunks per lane: 4 * 64 lanes * 4 floats = 1024

__global__ __launch_bounds__(256) void reskip_router_kernel(
    const float* __restrict__ blocks,     // [NBLK, BT, D]
    const float* __restrict__ partial,    // [BT, D]
    const float* __restrict__ w_query,    // [D]
    const float* __restrict__ norm_w,     // [D]
    float* __restrict__ out_hidden,       // [BT, D]
    float* __restrict__ out_entropy,      // [BT]
    int BT)
{
    const int wave = threadIdx.x >> 6;
    const int lane = threadIdx.x & 63;
    const int tok  = blockIdx.x * 4 + wave;
    if (tok >= BT) return;

    const float inv_d     = 1.0f / (float)D;
    const float inv_scale = 1.0f / 32.0f;   // 1/(sqrt(1024)*temperature)
    const float eps       = 1e-6f;

    // effective query: w_query * norm_weight (fp32), lane-local 16 floats
    const float4* wq4 = (const float4*)w_query;
    const float4* nw4 = (const float4*)norm_w;
    float4 q[C4];
#pragma unroll
    for (int c = 0; c < C4; ++c) {
        float4 a = wq4[c * 64 + lane];
        float4 b = nw4[c * 64 + lane];
        q[c] = make_float4(a.x * b.x, a.y * b.y, a.z * b.z, a.w * b.w);
    }

    const size_t tokOff = (size_t)tok * D;

    // online softmax state
    float m = -INFINITY;   // running max score
    float l = 0.0f;        // running lse
    float4 r[C4];          // running routed accumulator (unnormalized)
#pragma unroll
    for (int c = 0; c < C4; ++c) r[c] = make_float4(0.f, 0.f, 0.f, 0.f);
    float scores[NBLK];

#pragma unroll
    for (int i = 0; i < NBLK; ++i) {
        const float4* src = (const float4*)(blocks + (size_t)i * BT * D + tokOff);
        float4 s[C4];
        float ss = 0.0f, dt = 0.0f;
#pragma unroll
        for (int c = 0; c < C4; ++c) {
            float4 v = src[c * 64 + lane];
            s[c] = v;
            ss += v.x * v.x + v.y * v.y + v.z * v.z + v.w * v.w;
            dt += q[c].x * v.x + q[c].y * v.y + q[c].z * v.z + q[c].w * v.w;
        }
        // wave-wide reduction of (ss, dt)
#pragma unroll
        for (int off = 32; off > 0; off >>= 1) {
            ss += __shfl_xor(ss, off, 64);
            dt += __shfl_xor(dt, off, 64);
        }
        float inv = rsqrtf(ss * inv_d + eps);
        float sc  = dt * inv * inv_scale;
        scores[i] = sc;

        float nm    = fmaxf(m, sc);
        float alpha = expf(m - nm);      // m=-inf first iter -> alpha=0
        float e     = expf(sc - nm);
        l = l * alpha + e;
#pragma unroll
        for (int c = 0; c < C4; ++c) {
            r[c].x = r[c].x * alpha + e * s[c].x;
            r[c].y = r[c].y * alpha + e * s[c].y;
            r[c].z = r[c].z * alpha + e * s[c].z;
            r[c].w = r[c].w * alpha + e * s[c].w;
        }
        m = nm;
    }

    // phase-1 entropy: log(L) - (1/L) * sum_i e^{s_i-M} (s_i-M)
    float T = 0.0f;
#pragma unroll
    for (int i = 0; i < NBLK; ++i) {
        float sh = scores[i] - m;
        T += expf(sh) * sh;
    }
    float p1_ent = logf(l) - T / l;

    // partial block: score + merge
    const float4* pp = (const float4*)(partial + tokOff);
    float4 p[C4];
    float pss = 0.0f, pdt = 0.0f;
#pragma unroll
    for (int c = 0; c < C4; ++c) {
        float4 v = pp[c * 64 + lane];
        p[c] = v;
        pss += v.x * v.x + v.y * v.y + v.z * v.z + v.w * v.w;
        pdt += q[c].x * v.x + q[c].y * v.y + q[c].z * v.z + q[c].w * v.w;
    }
#pragma unroll
    for (int off = 32; off > 0; off >>= 1) {
        pss += __shfl_xor(pss, off, 64);
        pdt += __shfl_xor(pdt, off, 64);
    }
    float pinv = rsqrtf(pss * inv_d + eps);
    float psc  = pdt * pinv * inv_scale;

    float mm    = fmaxf(m, psc);
    float c1    = expf(m - mm);
    float cp    = expf(psc - mm);
    float denom = c1 * l + cp;
    float w1    = c1 * l / denom;   // phase1_weight
    float wp    = cp / denom;       // partial_weight

    // hidden = routed * w1 + partial * wp   (routed left unnormalized, per ref)
    float4* outp = (float4*)(out_hidden + tokOff);
#pragma unroll
    for (int c = 0; c < C4; ++c) {
        float4 o;
        o.x = r[c].x * w1 + p[c].x * wp;
        o.y = r[c].y * w1 + p[c].y * wp;
        o.z = r[c].z * w1 + p[c].z * wp;
        o.w = r[c].w * w1 + p[c].w * wp;
        outp[c * 64 + lane] = o;
    }

    if (lane == 0) {
        float w1c = fmaxf(w1, 1e-8f);
        float wpc = fmaxf(wp, 1e-8f);
        out_entropy[tok] = w1c * p1_ent - w1c * logf(w1c) - wpc * logf(wpc);
    }
}

extern "C" void kernel_launch(void* const* d_in, const int* in_sizes, int n_in,
                              void* d_out, int out_size, void* d_ws, size_t ws_size,
                              hipStream_t stream) {
    const float* blocks  = (const float*)d_in[0];   // [6, b, t, d]
    const float* partial = (const float*)d_in[1];   // [b, t, d]
    const float* wq      = (const float*)d_in[2];   // [d]
    const float* nw      = (const float*)d_in[3];   // [d]
    float* out = (float*)d_out;

    const int BT = in_sizes[1] / D;                 // b*t
    float* out_hidden  = out;
    float* out_entropy = out + (size_t)BT * D;

    const int grid = (BT + 3) / 4;                  // 4 tokens (waves) per block
    reskip_router_kernel<<<grid, 256, 0, stream>>>(
        blocks, partial, wq, nw, out_hidden, out_entropy, BT);
}

// Round 3
// 286.047 us; speedup vs baseline: 1.0749x; 1.0749x over previous
//
#include <hip/hip_runtime.h>
#include <math.h>

// ReSkipBlockGroup router: fused rms-norm scoring + online-softmax routing
// over n=6 completed blocks, merged with a partial block.
//
// Shapes: blocks [6, B*T, 1024] fp32, partial [B*T, 1024] fp32,
// w_query/norm_weight [1024] fp32. Output: hidden [B*T,1024] ++ entropy [B*T].
//
// One 64-lane wave per token; each lane owns 4 coalesced float4 chunks
// (16 floats). Single pass, online softmax, with an explicit 2-deep
// software pipeline: block i+1 (and finally the partial block) is loaded
// into a rotating register buffer while block i is reduced/rescaled.
// All bulk traffic is nontemporal (pure stream, zero reuse).
// Memory-bound: ~269 MB total traffic -> roofline ~43 us @ 6.3 TB/s.

#define D 1024
#define NBLK 6
#define C4 4              // float4 chunks per lane: 4 * 64 lanes * 4 floats = 1024

// native vector type — __builtin_nontemporal_* requires this, not HIP_vector_type
typedef float vf4 __attribute__((ext_vector_type(4)));

__global__ __launch_bounds__(256) void reskip_router_kernel(
    const float* __restrict__ blocks,     // [NBLK, BT, D]
    const float* __restrict__ partial,    // [BT, D]
    const float* __restrict__ w_query,    // [D]
    const float* __restrict__ norm_w,     // [D]
    float* __restrict__ out_hidden,       // [BT, D]
    float* __restrict__ out_entropy,      // [BT]
    int BT)
{
    const int wave = threadIdx.x >> 6;
    const int lane = threadIdx.x & 63;
    const int tok  = blockIdx.x * 4 + wave;
    if (tok >= BT) return;

    const float inv_d     = 1.0f / (float)D;
    const float inv_scale = 1.0f / 32.0f;   // 1/(sqrt(1024)*temperature)
    const float eps       = 1e-6f;

    // effective query: w_query * norm_weight (fp32), lane-local 16 floats.
    // (normal loads — tiny, shared across all waves, let L2 keep it)
    const vf4* wq4 = (const vf4*)w_query;
    const vf4* nw4 = (const vf4*)norm_w;
    vf4 q[C4];
#pragma unroll
    for (int c = 0; c < C4; ++c) {
        q[c] = wq4[c * 64 + lane] * nw4[c * 64 + lane];
    }

    const size_t tokOff    = (size_t)tok * D;
    const size_t blkStride = (size_t)BT * D;

    // rotating 2-deep register buffer for the software pipeline
    vf4 buf[2][C4];

    // prologue: load block 0
    {
        const vf4* p0 = (const vf4*)(blocks + tokOff);
#pragma unroll
        for (int c = 0; c < C4; ++c)
            buf[0][c] = __builtin_nontemporal_load(&p0[c * 64 + lane]);
    }

    // online softmax state
    float m = -INFINITY;
    float l = 0.0f;
    vf4 r[C4];
#pragma unroll
    for (int c = 0; c < C4; ++c) r[c] = (vf4)(0.f);
    float scores[NBLK];

#pragma unroll
    for (int i = 0; i < NBLK; ++i) {
        vf4* cur = buf[i & 1];
        vf4* nxt = buf[(i + 1) & 1];

        // prefetch next stream (block i+1, or the partial block on the last iter)
        const vf4* pn = (i + 1 < NBLK)
            ? (const vf4*)(blocks + (size_t)(i + 1) * blkStride + tokOff)
            : (const vf4*)(partial + tokOff);
#pragma unroll
        for (int c = 0; c < C4; ++c)
            nxt[c] = __builtin_nontemporal_load(&pn[c * 64 + lane]);

        // reduce current block: sumsq + dot(query)
        float ss = 0.0f, dt = 0.0f;
#pragma unroll
        for (int c = 0; c < C4; ++c) {
            vf4 v = cur[c];
            ss += v.x * v.x + v.y * v.y + v.z * v.z + v.w * v.w;
            dt += q[c].x * v.x + q[c].y * v.y + q[c].z * v.z + q[c].w * v.w;
        }
#pragma unroll
        for (int off = 32; off > 0; off >>= 1) {
            ss += __shfl_xor(ss, off, 64);
            dt += __shfl_xor(dt, off, 64);
        }
        float inv = rsqrtf(ss * inv_d + eps);
        float sc  = dt * inv * inv_scale;
        scores[i] = sc;

        float nm    = fmaxf(m, sc);
        float alpha = expf(m - nm);      // m=-inf first iter -> alpha=0
        float e     = expf(sc - nm);
        l = l * alpha + e;
#pragma unroll
        for (int c = 0; c < C4; ++c) {
            r[c] = r[c] * alpha + cur[c] * e;
        }
        m = nm;
    }

    // phase-1 entropy: log(L) - (1/L) * sum_i e^{s_i-M} (s_i-M)
    float T = 0.0f;
#pragma unroll
    for (int i = 0; i < NBLK; ++i) {
        float sh = scores[i] - m;
        T += expf(sh) * sh;
    }
    float p1_ent = logf(l) - T / l;

    // partial block (already prefetched into buf[NBLK & 1]): score + merge
    vf4* p = buf[NBLK & 1];
    float pss = 0.0f, pdt = 0.0f;
#pragma unroll
    for (int c = 0; c < C4; ++c) {
        vf4 v = p[c];
        pss += v.x * v.x + v.y * v.y + v.z * v.z + v.w * v.w;
        pdt += q[c].x * v.x + q[c].y * v.y + q[c].z * v.z + q[c].w * v.w;
    }
#pragma unroll
    for (int off = 32; off > 0; off >>= 1) {
        pss += __shfl_xor(pss, off, 64);
        pdt += __shfl_xor(pdt, off, 64);
    }
    float pinv = rsqrtf(pss * inv_d + eps);
    float psc  = pdt * pinv * inv_scale;

    float mm    = fmaxf(m, psc);
    float c1    = expf(m - mm);
    float cp    = expf(psc - mm);
    float denom = c1 * l + cp;
    float w1    = c1 * l / denom;   // phase1_weight
    float wp    = cp / denom;       // partial_weight

    // hidden = routed * w1 + partial * wp  (routed left unnormalized, per ref)
    vf4* outp = (vf4*)(out_hidden + tokOff);
#pragma unroll
    for (int c = 0; c < C4; ++c) {
        vf4 o = r[c] * w1 + p[c] * wp;
        __builtin_nontemporal_store(o, &outp[c * 64 + lane]);
    }

    if (lane == 0) {
        float w1c = fmaxf(w1, 1e-8f);
        float wpc = fmaxf(wp, 1e-8f);
        out_entropy[tok] = w1c * p1_ent - w1c * logf(w1c) - wpc * logf(wpc);
    }
}

extern "C" void kernel_launch(void* const* d_in, const int* in_sizes, int n_in,
                              void* d_out, int out_size, void* d_ws, size_t ws_size,
                              hipStream_t stream) {
    const float* blocks  = (const float*)d_in[0];   // [6, b, t, d]
    const float* partial = (const float*)d_in[1];   // [b, t, d]
    const float* wq      = (const float*)d_in[2];   // [d]
    const float* nw      = (const float*)d_in[3];   // [d]
    float* out = (float*)d_out;

    const int BT = in_sizes[1] / D;                 // b*t
    float* out_hidden  = out;
    float* out_entropy = out + (size_t)BT * D;

    const int grid = (BT + 3) / 4;                  // 4 tokens (waves) per block
    reskip_router_kernel<<<grid, 256, 0, stream>>>(
        blocks, partial, wq, nw, out_hidden, out_entropy, BT);
}